// Round 3
// baseline (412.594 us; speedup 1.0000x reference)
//
#include <hip/hip_runtime.h>
#include <hip/hip_cooperative_groups.h>
#include <math.h>

namespace cg = cooperative_groups;

#define SQ   2048
#define DH   128
#define NKT  32            // SQ/64 key tiles
#define SCALEF  0.08838834764831845f   // 1/sqrt(128)  (fallback path)
#define SCALE2  0.12751743f            // (1/sqrt(128)) * log2(e)
#define NSHIFT2 (-23.083121f)          // -16 * log2(e)  (fixed softmax shift, exp2 domain)

typedef __attribute__((ext_vector_type(8))) short bf16x8;
typedef __attribute__((ext_vector_type(4))) float f32x4;

__device__ __forceinline__ unsigned short f2b(float f) {
    unsigned int u = __float_as_uint(f);
    u += 0x7FFFu + ((u >> 16) & 1u);
    return (unsigned short)(u >> 16);
}
// RNE pack of two f32 -> bf16x2 in one VALU op (gfx950)
__device__ __forceinline__ unsigned int cvtpk(float lo, float hi) {
    unsigned int r;
    asm("v_cvt_pk_bf16_f32 %0, %1, %2" : "=v"(r) : "v"(lo), "v"(hi));
    return r;
}
// 2^x via v_exp_f32
__device__ __forceinline__ float fexp2(float x) {
    float r;
    asm("v_exp_f32 %0, %1" : "=v"(r) : "v"(x));
    return r;
}

typedef __attribute__((address_space(1))) const unsigned int guint;
typedef __attribute__((address_space(3))) unsigned int luint;
__device__ __forceinline__ void load_lds16(const void* g, void* l) {
    __builtin_amdgcn_global_load_lds((guint*)g, (luint*)l, 16, 0, 0);
}

// ---------------- LAYOUTS (bank-conflict-swizzled, v2) ----------------
// K tile (bh,kt): chunk id = (ks*64+key)*4+q', content K[key][ks*32+(q'^((key>>1)&3))*8+j]
// V tile (bh,kt): chunk id = (ks2*128+d)*4+q', content V[ks2*32+(q'^((d>>1)&3))*8+j][d]
// Reader with (quad,c) uses slot q' = quad ^ ((c>>1)&3): conflict-light.

// ---------------- prep device pieces (shared by fused & fallback paths) -----
__device__ __forceinline__ void prep_k_piece(const float* __restrict__ K,
                                             unsigned short* __restrict__ Kp, int id)
{
    int quad = id & 3;
    int key  = (id >> 2) & 63;
    int ks   = (id >> 8) & 3;
    int kt   = (id >> 10) & 31;
    int bh   = id >> 15;
    int qsrc = quad ^ ((key >> 1) & 3);
    const float* src = K + (size_t)(kt * 64 + key) * 4096 + bh * DH + ks * 32 + qsrc * 8;
    float4 f0 = *(const float4*)src;
    float4 f1 = *(const float4*)(src + 4);
    uint4 o;
    o.x = cvtpk(f0.x, f0.y); o.y = cvtpk(f0.z, f0.w);
    o.z = cvtpk(f1.x, f1.y); o.w = cvtpk(f1.z, f1.w);
    *(uint4*)(Kp + (size_t)id * 8) = o;
}

__device__ __forceinline__ void prep_v_piece(const float* __restrict__ V,
                                             unsigned short* __restrict__ Vp,
                                             int t, int tid)
{
    int kt   = t & 31, bh = t >> 5;
    int quad = tid & 3;
    int d2   = tid >> 2;                // 0..63
    int s    = (d2 >> 1) & 3;
    int rb   = (quad ^ s) * 8;
    unsigned short* ob = Vp + (size_t)t * 8192;
    #pragma unroll
    for (int ks2 = 0; ks2 < 2; ks2++) {
        #pragma unroll
        for (int dhi = 0; dhi < 2; dhi++) {
            int d = dhi * 64 + d2;
            const float* vb = V + (size_t)(kt * 64 + ks2 * 32 + rb) * 4096 + bh * DH + d;
            float f[8];
            #pragma unroll
            for (int j = 0; j < 8; j++)
                f[j] = vb[(size_t)j * 4096];
            uint4 o;
            o.x = cvtpk(f[0], f[1]); o.y = cvtpk(f[2], f[3]);
            o.z = cvtpk(f[4], f[5]); o.w = cvtpk(f[6], f[7]);
            *(uint4*)(ob + ((size_t)(ks2 * 128 + d) * 4 + quad) * 8) = o;
        }
    }
}

__device__ __forceinline__ void prep_m_piece(const int* __restrict__ M,
                                             unsigned long long* __restrict__ B,
                                             int b2, int tid)
{
    int wid  = b2 * 4 + (tid >> 6);     // row in [0,4096)
    int lane = tid & 63;
    const int* src = M + (size_t)wid * SQ + lane;
    unsigned long long* dst = B + (size_t)wid * NKT;
    #pragma unroll
    for (int t = 0; t < NKT; t++) {
        unsigned long long bm = __ballot(src[t * 64] != 0);
        if (lane == 0) dst[t] = bm;
    }
}

// ---------------- standalone prep (fallback path) ----------------
__global__ __launch_bounds__(256)
void prep_all(const float* __restrict__ K, const float* __restrict__ V,
              const int* __restrict__ M,
              unsigned short* __restrict__ Kp, unsigned short* __restrict__ Vp,
              unsigned long long* __restrict__ B)
{
    const int bid = blockIdx.x;
    const int tid = threadIdx.x;
    if (bid < 4096)       prep_k_piece(K, Kp, bid * 256 + tid);
    else if (bid < 5120)  prep_v_piece(V, Vp, bid - 4096, tid);
    else                  prep_m_piece(M, B, bid - 5120, tid);
}

// ---------------- attention body (shared: fa2 + fused) ----------------
#define STAGE(Kl, Vl, ktt) do {                                              \
    const unsigned short* kg_ = KpT + (size_t)(ktt) * 8192;                  \
    const unsigned short* vg_ = VpT + (size_t)(ktt) * 8192;                  \
    _Pragma("unroll") for (int i_ = 0; i_ < 4; i_++) {                       \
        int ch_ = w * 64 + i_ * 256;                                         \
        load_lds16(kg_ + (size_t)(ch_ + lane) * 8, &Kl[ch_ * 8]);            \
    }                                                                        \
    _Pragma("unroll") for (int i_ = 0; i_ < 4; i_++) {                       \
        int ch_ = w * 64 + i_ * 256;                                         \
        load_lds16(vg_ + (size_t)(ch_ + lane) * 8, &Vl[ch_ * 8]);            \
    }                                                                        \
} while (0)

#define LOADMR(mr, ktt) do {                                                 \
    _Pragma("unroll") for (int r_ = 0; r_ < 4; r_++) {                       \
        mr[0][r_] = mb0[r_ * NKT + (ktt)];                                   \
        mr[1][r_] = mb1[r_ * NKT + (ktt)];                                   \
    }                                                                        \
} while (0)

#define COMPUTE(Kl, Vl, mr) do {                                             \
    f32x4 s[2][4];                                                           \
    _Pragma("unroll") for (int blk = 0; blk < 2; blk++)                      \
        _Pragma("unroll") for (int nb = 0; nb < 4; nb++)                     \
            s[blk][nb] = (f32x4){0.f, 0.f, 0.f, 0.f};                        \
    __builtin_amdgcn_s_setprio(1);                                           \
    _Pragma("unroll") for (int nb = 0; nb < 4; nb++) {                       \
        bf16x8 bk[4];                                                        \
        _Pragma("unroll") for (int ks = 0; ks < 4; ks++)                     \
            bk[ks] = *(const bf16x8*)&Kl[ks * 2048 + nb * 512 + c * 32 + swz8]; \
        _Pragma("unroll") for (int blk = 0; blk < 2; blk++)                  \
            _Pragma("unroll") for (int ks = 0; ks < 4; ks++)                 \
                s[blk][nb] = __builtin_amdgcn_mfma_f32_16x16x32_bf16(aq[blk][ks], bk[ks], s[blk][nb], 0, 0, 0); \
    }                                                                        \
    __builtin_amdgcn_s_setprio(0);                                           \
    _Pragma("unroll") for (int blk = 0; blk < 2; blk++) {                    \
        _Pragma("unroll") for (int r = 0; r < 4; r++) {                      \
            unsigned long long bits = mr[blk][r];                            \
            unsigned wlo = (unsigned)(bits >> c);                            \
            unsigned whi = (unsigned)(bits >> 32) >> c;                      \
            _Pragma("unroll") for (int nbp = 0; nbp < 2; nbp++) {            \
                unsigned wb = nbp ? whi : wlo;                               \
                float p0 = fexp2(fmaf(s[blk][2 * nbp][r],     SCALE2, NSHIFT2)); \
                float p1 = fexp2(fmaf(s[blk][2 * nbp + 1][r], SCALE2, NSHIFT2)); \
                if (wb & 1u)       p0 = 0.0f;                                \
                if (wb & 0x10000u) p1 = 0.0f;                                \
                l[blk][r] += p0 + p1;                                        \
                unsigned pk = cvtpk(p0, p1);                                 \
                int base = nbp * 1024 + blk * 512 + quad * 128 + r * 32 + (c & 7); \
                Pw[base + ((0 + (c >> 3)) ^ quad) * 8] = (unsigned short)pk; \
                Pw[base + ((2 + (c >> 3)) ^ quad) * 8] = (unsigned short)(pk >> 16); \
            }                                                                \
        }                                                                    \
    }                                                                        \
    bf16x8 ap[2][2];                                                         \
    _Pragma("unroll") for (int blk = 0; blk < 2; blk++)                      \
        _Pragma("unroll") for (int ks2 = 0; ks2 < 2; ks2++)                  \
            ap[blk][ks2] = *(const bf16x8*)&Pw[ks2 * 1024 + blk * 512 + c * 32 + ((quad ^ (c >> 2)) * 8)]; \
    __builtin_amdgcn_s_setprio(1);                                           \
    _Pragma("unroll") for (int nb = 0; nb < 8; nb++) {                       \
        bf16x8 bv0 = *(const bf16x8*)&Vl[nb * 512 + c * 32 + swz8];          \
        bf16x8 bv1 = *(const bf16x8*)&Vl[4096 + nb * 512 + c * 32 + swz8];   \
        _Pragma("unroll") for (int blk = 0; blk < 2; blk++) {                \
            oa[blk][nb] = __builtin_amdgcn_mfma_f32_16x16x32_bf16(ap[blk][0], bv0, oa[blk][nb], 0, 0, 0); \
            oa[blk][nb] = __builtin_amdgcn_mfma_f32_16x16x32_bf16(ap[blk][1], bv1, oa[blk][nb], 0, 0, 0); \
        }                                                                    \
    }                                                                        \
    __builtin_amdgcn_s_setprio(0);                                           \
} while (0)

// One pipeline step: barA | stage nxt + prefetch next mask rows | counted
// vmcnt(16) | barB | compute(cur).  Raw barriers: no implicit vmcnt(0) drain.
#define PIPE_STEP(Kc, Vc, mrC, Kn, Vn, mrN, ktn) do {                        \
    __builtin_amdgcn_s_barrier();                                            \
    STAGE(Kn, Vn, (ktn));                                                    \
    LOADMR(mrN, (ktn));                                                      \
    asm volatile("s_waitcnt vmcnt(16)" ::: "memory");                        \
    __builtin_amdgcn_s_barrier();                                            \
    __builtin_amdgcn_sched_barrier(0);                                       \
    COMPUTE(Kc, Vc, mrC);                                                    \
} while (0)

__device__ __forceinline__ void attn_body(
    const float* __restrict__ Q, const unsigned short* __restrict__ Kp,
    const unsigned short* __restrict__ Vp, const unsigned long long* __restrict__ MB,
    float* __restrict__ out,
    unsigned short (*K_lds)[64 * 128], unsigned short (*V_lds)[64 * 128],
    unsigned short* P_lds)
{
    const int tid  = threadIdx.x;
    const int w    = tid >> 6;
    const int lane = tid & 63;
    const int quad = lane >> 4;
    const int c    = lane & 15;
    // K/V LDS read slot: conflict-light swizzle
    const int swz8 = (quad ^ ((c >> 1) & 3)) * 8;

    // XCD-aware swizzle: each XCD gets 4 full bh groups (64 blocks)
    const int bid0 = blockIdx.x;
    const int bid  = ((bid0 & 7) << 6) | (bid0 >> 3);
    const int qt  = bid & 15;
    const int bh  = bid >> 4;
    const int b_i = bh >> 4;
    const int qbase = qt * 128 + w * 32;
    const size_t bh_off = (size_t)bh * DH;

    // Q fragments (A-operand): aq[blk][ks], rows qbase+blk*16+c
    bf16x8 aq[2][4];
    #pragma unroll
    for (int blk = 0; blk < 2; blk++) {
        const float* qrow = Q + (size_t)(qbase + blk * 16 + c) * 4096 + bh_off;
        #pragma unroll
        for (int ks = 0; ks < 4; ks++) {
            const int d0 = ks * 32 + quad * 8;
            float4 f0 = *(const float4*)(qrow + d0);
            float4 f1 = *(const float4*)(qrow + d0 + 4);
            uint4 u;
            u.x = cvtpk(f0.x, f0.y); u.y = cvtpk(f0.z, f0.w);
            u.z = cvtpk(f1.x, f1.y); u.w = cvtpk(f1.z, f1.w);
            aq[blk][ks] = *(bf16x8*)&u;
        }
    }

    f32x4 oa[2][8];
    #pragma unroll
    for (int blk = 0; blk < 2; blk++)
        #pragma unroll
        for (int nb = 0; nb < 8; nb++) oa[blk][nb] = (f32x4){0.f, 0.f, 0.f, 0.f};
    float l[2][4];
    #pragma unroll
    for (int blk = 0; blk < 2; blk++)
        #pragma unroll
        for (int r = 0; r < 4; r++) l[blk][r] = 0.0f;

    const unsigned short* KpT = Kp + (size_t)bh * (NKT * 8192);
    const unsigned short* VpT = Vp + (size_t)bh * (NKT * 8192);
    const unsigned long long* mb0 = MB + (size_t)(b_i * SQ + qbase + quad * 4) * NKT;
    const unsigned long long* mb1 = mb0 + 16 * NKT;
    unsigned short* Pw = &P_lds[w * 2048];

    unsigned long long mrA[2][4], mrB[2][4];

    // prologue: stage tile 0 + its mask rows
    STAGE(K_lds[0], V_lds[0], 0);
    LOADMR(mrA, 0);

    for (int kt = 0; kt < NKT; kt += 2) {
        PIPE_STEP(K_lds[0], V_lds[0], mrA, K_lds[1], V_lds[1], mrB, kt + 1);
        PIPE_STEP(K_lds[1], V_lds[1], mrB, K_lds[0], V_lds[0], mrA, (kt + 2) & 31);
    }
    asm volatile("s_waitcnt vmcnt(0)" ::: "memory");

    // epilogue: reduce l across 16 lanes, 1/l (0 if all masked), store
    #pragma unroll
    for (int blk = 0; blk < 2; blk++) {
        #pragma unroll
        for (int r = 0; r < 4; r++) {
            float t = l[blk][r];
            t += __shfl_xor(t, 1, 64);
            t += __shfl_xor(t, 2, 64);
            t += __shfl_xor(t, 4, 64);
            t += __shfl_xor(t, 8, 64);
            float inv = (t > 0.0f) ? (1.0f / t) : 0.0f;
            float* orow = out + (size_t)(qbase + blk * 16 + quad * 4 + r) * 4096 + bh_off;
            #pragma unroll
            for (int nb = 0; nb < 8; nb++)
                orow[nb * 16 + c] = oa[blk][nb][r] * inv;
        }
    }
}

// ---------------- standalone fa2 (fallback path) ----------------
__global__ __launch_bounds__(256, 2)
void fa2(const float* __restrict__ Q, const unsigned short* __restrict__ Kp,
         const unsigned short* __restrict__ Vp, const unsigned long long* __restrict__ MB,
         float* __restrict__ out)
{
    __shared__ __align__(16) unsigned short K_lds[2][64 * 128];
    __shared__ __align__(16) unsigned short V_lds[2][64 * 128];
    __shared__ __align__(16) unsigned short P_lds[4 * 2048];
    attn_body(Q, Kp, Vp, MB, out, K_lds, V_lds, P_lds);
}

// ---------------- fused cooperative kernel: prep + grid.sync + attention ----
// 512 blocks x 256 thr, 80KB LDS, <=128 VGPR -> exactly 2 blocks/CU resident.
__global__ __launch_bounds__(256, 2)
void fa2_fused(const float* __restrict__ Q, const float* __restrict__ K,
               const float* __restrict__ V, const int* __restrict__ M,
               unsigned short* __restrict__ Kp, unsigned short* __restrict__ Vp,
               unsigned long long* __restrict__ MB, float* __restrict__ out)
{
    __shared__ __align__(16) unsigned short K_lds[2][64 * 128];
    __shared__ __align__(16) unsigned short V_lds[2][64 * 128];
    __shared__ __align__(16) unsigned short P_lds[4 * 2048];

    const int bid = blockIdx.x;
    const int tid = threadIdx.x;

    // ---- phase 1: prep, original 6144-block work distributed over 512 ----
    {
        #pragma unroll
        for (int i = 0; i < 8; i++)                       // K: 4096 blk -> 8x
            prep_k_piece(K, Kp, (bid * 256 + tid) + i * (512 * 256));
        #pragma unroll
        for (int i = 0; i < 2; i++)                       // V: 1024 blk -> 2x
            prep_v_piece(V, Vp, bid * 2 + i, tid);
        #pragma unroll
        for (int i = 0; i < 2; i++)                       // M: 1024 blk -> 2x
            prep_m_piece(M, MB, bid * 2 + i, tid);
    }
    __threadfence();
    cg::this_grid().sync();

    // ---- phase 2: attention (identical to fa2) ----
    attn_body(Q, Kp, Vp, MB, out, K_lds, V_lds, P_lds);
}

// ---------------- fallback if workspace too small (unchanged) ----------------
__global__ __launch_bounds__(256)
void fa_fallback(const float* __restrict__ Q, const float* __restrict__ K,
                 const float* __restrict__ V, const int* __restrict__ mask,
                 float* __restrict__ out)
{
    __shared__ unsigned short K_lds[64 * 136];
    __shared__ unsigned short Vt_lds[128 * 72];
    __shared__ unsigned short P_lds[4 * 16 * 72];
    const int tid = threadIdx.x, w = tid >> 6, lane = tid & 63, quad = lane >> 4, c = lane & 15;
    const int gid = blockIdx.x, qtile = gid & 31, bh = gid >> 5, b_i = bh >> 4;
    const int q0 = qtile * 64 + w * 16;
    const size_t bh_off = (size_t)bh * DH;
    bf16x8 aq[4];
    {
        const float* qrow = Q + (size_t)(q0 + c) * 4096 + bh_off;
        #pragma unroll
        for (int ks = 0; ks < 4; ks++) {
            const int d0 = ks * 32 + quad * 8;
            float4 f0 = *(const float4*)(qrow + d0);
            float4 f1 = *(const float4*)(qrow + d0 + 4);
            bf16x8 a;
            a[0] = (short)f2b(f0.x); a[1] = (short)f2b(f0.y); a[2] = (short)f2b(f0.z); a[3] = (short)f2b(f0.w);
            a[4] = (short)f2b(f1.x); a[5] = (short)f2b(f1.y); a[6] = (short)f2b(f1.z); a[7] = (short)f2b(f1.w);
            aq[ks] = a;
        }
    }
    float m_i[4], l_i[4];
    #pragma unroll
    for (int r = 0; r < 4; r++) { m_i[r] = -INFINITY; l_i[r] = 0.0f; }
    f32x4 o_acc[8];
    #pragma unroll
    for (int nb = 0; nb < 8; nb++) o_acc[nb] = (f32x4){0.f, 0.f, 0.f, 0.f};
    const int srow = tid >> 2, scol = (tid & 3) * 4;
    const int* mbase = mask + (size_t)b_i * SQ * SQ;
    for (int kt = 0; kt < SQ; kt += 64) {
        __syncthreads();
        {
            const float* krow = K + (size_t)(kt + srow) * 4096 + bh_off;
            const float* vrow = V + (size_t)(kt + srow) * 4096 + bh_off;
            #pragma unroll
            for (int j = 0; j < 8; j++) {
                const int d0 = scol + j * 16;
                float4 kf = *(const float4*)(krow + d0);
                unsigned lo = (unsigned)f2b(kf.x) | ((unsigned)f2b(kf.y) << 16);
                unsigned hi = (unsigned)f2b(kf.z) | ((unsigned)f2b(kf.w) << 16);
                *(uint2*)&K_lds[srow * 136 + d0] = make_uint2(lo, hi);
                float4 vf = *(const float4*)(vrow + d0);
                Vt_lds[(d0 + 0) * 72 + srow] = f2b(vf.x);
                Vt_lds[(d0 + 1) * 72 + srow] = f2b(vf.y);
                Vt_lds[(d0 + 2) * 72 + srow] = f2b(vf.z);
                Vt_lds[(d0 + 3) * 72 + srow] = f2b(vf.w);
            }
        }
        __syncthreads();
        f32x4 s[4];
        #pragma unroll
        for (int nb = 0; nb < 4; nb++) s[nb] = (f32x4){0.f, 0.f, 0.f, 0.f};
        #pragma unroll
        for (int nb = 0; nb < 4; nb++)
            #pragma unroll
            for (int ks = 0; ks < 4; ks++) {
                bf16x8 bk = *(const bf16x8*)&K_lds[(nb * 16 + c) * 136 + ks * 32 + quad * 8];
                s[nb] = __builtin_amdgcn_mfma_f32_16x16x32_bf16(aq[ks], bk, s[nb], 0, 0, 0);
            }
        float rowmax[4];
        #pragma unroll
        for (int r = 0; r < 4; r++) rowmax[r] = -INFINITY;
        #pragma unroll
        for (int r = 0; r < 4; r++) {
            const int* mp = mbase + (size_t)(q0 + quad * 4 + r) * SQ + kt + c;
            #pragma unroll
            for (int nb = 0; nb < 4; nb++) {
                float v = s[nb][r] * SCALEF;
                if (mp[nb * 16] != 0) v = -10000.0f;
                s[nb][r] = v;
                rowmax[r] = fmaxf(rowmax[r], v);
            }
        }
        #pragma unroll
        for (int r = 0; r < 4; r++)
            #pragma unroll
            for (int off = 1; off < 16; off <<= 1)
                rowmax[r] = fmaxf(rowmax[r], __shfl_xor(rowmax[r], off, 64));
        float alpha[4], rowsum[4];
        #pragma unroll
        for (int r = 0; r < 4; r++) {
            float mn = fmaxf(m_i[r], rowmax[r]);
            alpha[r] = __expf(m_i[r] - mn);
            m_i[r] = mn;
            rowsum[r] = 0.0f;
        }
        #pragma unroll
        for (int r = 0; r < 4; r++)
            #pragma unroll
            for (int nb = 0; nb < 4; nb++) {
                float p = __expf(s[nb][r] - m_i[r]);
                rowsum[r] += p;
                P_lds[(w * 16 + quad * 4 + r) * 72 + nb * 16 + c] = f2b(p);
            }
        #pragma unroll
        for (int r = 0; r < 4; r++) {
            #pragma unroll
            for (int off = 1; off < 16; off <<= 1)
                rowsum[r] += __shfl_xor(rowsum[r], off, 64);
            l_i[r] = l_i[r] * alpha[r] + rowsum[r];
        }
        #pragma unroll
        for (int nb = 0; nb < 8; nb++)
            #pragma unroll
            for (int r = 0; r < 4; r++) o_acc[nb][r] *= alpha[r];
        bf16x8 ap[2];
        #pragma unroll
        for (int ks = 0; ks < 2; ks++)
            ap[ks] = *(const bf16x8*)&P_lds[(w * 16 + c) * 72 + ks * 32 + quad * 8];
        #pragma unroll
        for (int nb = 0; nb < 8; nb++)
            #pragma unroll
            for (int ks = 0; ks < 2; ks++) {
                bf16x8 bv = *(const bf16x8*)&Vt_lds[(nb * 16 + c) * 72 + ks * 32 + quad * 8];
                o_acc[nb] = __builtin_amdgcn_mfma_f32_16x16x32_bf16(ap[ks], bv, o_acc[nb], 0, 0, 0);
            }
    }
    float inv[4];
    #pragma unroll
    for (int r = 0; r < 4; r++) inv[r] = (m_i[r] > -9999.0f) ? (1.0f / l_i[r]) : 0.0f;
    #pragma unroll
    for (int r = 0; r < 4; r++) {
        float* orow = out + (size_t)(q0 + quad * 4 + r) * 4096 + bh_off;
        #pragma unroll
        for (int nb = 0; nb < 8; nb++) orow[nb * 16 + c] = o_acc[nb][r] * inv[r];
    }
}

extern "C" void kernel_launch(void* const* d_in, const int* in_sizes, int n_in,
                              void* d_out, int out_size, void* d_ws, size_t ws_size,
                              hipStream_t stream) {
    const float* Q    = (const float*)d_in[0];
    const float* K    = (const float*)d_in[1];
    const float* V    = (const float*)d_in[2];
    const int*   mask = (const int*)d_in[3];
    float* out = (float*)d_out;

    const size_t KP_BYTES = (size_t)32 * 32 * 8192 * 2;   // 16 MiB
    const size_t NEED = 2 * KP_BYTES + (size_t)4096 * NKT * 8;
    if (ws_size < NEED) {
        fa_fallback<<<dim3(1024), dim3(256), 0, stream>>>(Q, K, V, mask, out);
        return;
    }
    unsigned short* Kp = (unsigned short*)d_ws;
    unsigned short* Vp = (unsigned short*)((char*)d_ws + KP_BYTES);
    unsigned long long* MB = (unsigned long long*)((char*)d_ws + 2 * KP_BYTES);

    // Single cooperative dispatch: prep + grid.sync + attention.
    void* params[] = { (void*)&Q, (void*)&K, (void*)&V, (void*)&mask,
                       (void*)&Kp, (void*)&Vp, (void*)&MB, (void*)&out };
    hipError_t err = hipLaunchCooperativeKernel((const void*)fa2_fused,
                                                dim3(512), dim3(256),
                                                params, 0, stream);
    if (err != hipSuccess) {
        (void)hipGetLastError();   // clear sticky error, fall back to 2-dispatch
        prep_all<<<dim3(6144), dim3(256), 0, stream>>>(K, V, mask, Kp, Vp, MB);
        fa2<<<dim3(512), dim3(256), 0, stream>>>(Q, Kp, Vp, MB, out);
    }
}

// Round 4
// 288.591 us; speedup vs baseline: 1.4297x; 1.4297x over previous
//
#include <hip/hip_runtime.h>
#include <math.h>

#define SQ   2048
#define DH   128
#define NKT  32            // SQ/64 key tiles
#define SCALEF  0.08838834764831845f   // 1/sqrt(128)  (fallback path)
#define SCALE2  0.12751743f            // (1/sqrt(128)) * log2(e)
#define NSHIFT2 (-23.083121f)          // -16 * log2(e)  (fixed softmax shift, exp2 domain)

typedef __attribute__((ext_vector_type(8))) short bf16x8;
typedef __attribute__((ext_vector_type(4))) float f32x4;

__device__ __forceinline__ unsigned short f2b(float f) {
    unsigned int u = __float_as_uint(f);
    u += 0x7FFFu + ((u >> 16) & 1u);
    return (unsigned short)(u >> 16);
}
// RNE pack of two f32 -> bf16x2 in one VALU op (gfx950)
__device__ __forceinline__ unsigned int cvtpk(float lo, float hi) {
    unsigned int r;
    asm("v_cvt_pk_bf16_f32 %0, %1, %2" : "=v"(r) : "v"(lo), "v"(hi));
    return r;
}
// 2^x via v_exp_f32
__device__ __forceinline__ float fexp2(float x) {
    float r;
    asm("v_exp_f32 %0, %1" : "=v"(r) : "v"(x));
    return r;
}

typedef __attribute__((address_space(1))) const unsigned int guint;
typedef __attribute__((address_space(3))) unsigned int luint;
__device__ __forceinline__ void load_lds16(const void* g, void* l) {
    __builtin_amdgcn_global_load_lds((guint*)g, (luint*)l, 16, 0, 0);
}

// ---------------- LAYOUTS (bank-conflict-swizzled, validated R2v2) ----------
// K tile (bh,kt): chunk id = (ks*64+key)*4+q', content K[key][ks*32+(q'^((key>>1)&3))*8+j]
// V tile (bh,kt): chunk id = (ks2*128+d)*4+q', content V[ks2*32+(q'^((d>>1)&3))*8+j][d]
// Reader with (quad,c) uses slot q' = quad ^ ((c>>1)&3).

// ---------------- prep (validated R2 two-dispatch form) ----------------
__device__ __forceinline__ void prep_k_piece(const float* __restrict__ K,
                                             unsigned short* __restrict__ Kp, int id)
{
    int quad = id & 3;
    int key  = (id >> 2) & 63;
    int ks   = (id >> 8) & 3;
    int kt   = (id >> 10) & 31;
    int bh   = id >> 15;
    int qsrc = quad ^ ((key >> 1) & 3);
    const float* src = K + (size_t)(kt * 64 + key) * 4096 + bh * DH + ks * 32 + qsrc * 8;
    float4 f0 = *(const float4*)src;
    float4 f1 = *(const float4*)(src + 4);
    uint4 o;
    o.x = cvtpk(f0.x, f0.y); o.y = cvtpk(f0.z, f0.w);
    o.z = cvtpk(f1.x, f1.y); o.w = cvtpk(f1.z, f1.w);
    *(uint4*)(Kp + (size_t)id * 8) = o;
}

__device__ __forceinline__ void prep_v_piece(const float* __restrict__ V,
                                             unsigned short* __restrict__ Vp,
                                             int t, int tid)
{
    int kt   = t & 31, bh = t >> 5;
    int quad = tid & 3;
    int d2   = tid >> 2;                // 0..63
    int s    = (d2 >> 1) & 3;
    int rb   = (quad ^ s) * 8;
    unsigned short* ob = Vp + (size_t)t * 8192;
    #pragma unroll
    for (int ks2 = 0; ks2 < 2; ks2++) {
        #pragma unroll
        for (int dhi = 0; dhi < 2; dhi++) {
            int d = dhi * 64 + d2;
            const float* vb = V + (size_t)(kt * 64 + ks2 * 32 + rb) * 4096 + bh * DH + d;
            float f[8];
            #pragma unroll
            for (int j = 0; j < 8; j++)
                f[j] = vb[(size_t)j * 4096];
            uint4 o;
            o.x = cvtpk(f[0], f[1]); o.y = cvtpk(f[2], f[3]);
            o.z = cvtpk(f[4], f[5]); o.w = cvtpk(f[6], f[7]);
            *(uint4*)(ob + ((size_t)(ks2 * 128 + d) * 4 + quad) * 8) = o;
        }
    }
}

__device__ __forceinline__ void prep_m_piece(const int* __restrict__ M,
                                             unsigned long long* __restrict__ B,
                                             int b2, int tid)
{
    int wid  = b2 * 4 + (tid >> 6);     // row in [0,4096)
    int lane = tid & 63;
    const int* src = M + (size_t)wid * SQ + lane;
    unsigned long long* dst = B + (size_t)wid * NKT;
    #pragma unroll
    for (int t = 0; t < NKT; t++) {
        unsigned long long bm = __ballot(src[t * 64] != 0);
        if (lane == 0) dst[t] = bm;
    }
}

__global__ __launch_bounds__(256)
void prep_all(const float* __restrict__ K, const float* __restrict__ V,
              const int* __restrict__ M,
              unsigned short* __restrict__ Kp, unsigned short* __restrict__ Vp,
              unsigned long long* __restrict__ B)
{
    const int bid = blockIdx.x;
    const int tid = threadIdx.x;
    if (bid < 4096)       prep_k_piece(K, Kp, bid * 256 + tid);
    else if (bid < 5120)  prep_v_piece(V, Vp, bid - 4096, tid);
    else                  prep_m_piece(M, B, bid - 5120, tid);
}

// ---------------- fa3: high-occupancy attention ----------------
// 1024 blocks x 256 thr, 16 q-rows/wave, LDS 40KB -> 4 blocks/CU (16 waves/CU).
// Pipeline per step (2 __syncthreads, no counted vmcnt):
//   bar0 (implicit vmcnt0 publishes K(t) DMA'd mid-previous step)
//   STAGE_V(t) + LOADMR(t+1)      <- V hides under QK
//   QK(t)
//   bar1 (implicit vmcnt0 publishes V(t); guarantees K reads done)
//   STAGE_K(t+1)                  <- K hides under softmax+PV
//   softmax(t) -> P (wave-private LDS slice) -> PV(t)

#define STAGE_K3(ktt) do {                                                   \
    const unsigned short* kg_ = KpT + (size_t)(ktt) * 8192;                  \
    _Pragma("unroll") for (int i_ = 0; i_ < 4; i_++) {                       \
        int ch_ = w * 64 + i_ * 256;                                         \
        load_lds16(kg_ + (size_t)(ch_ + lane) * 8, &K_lds[ch_ * 8]);         \
    }                                                                        \
} while (0)

#define STAGE_V3(ktt) do {                                                   \
    const unsigned short* vg_ = VpT + (size_t)(ktt) * 8192;                  \
    _Pragma("unroll") for (int i_ = 0; i_ < 4; i_++) {                       \
        int ch_ = w * 64 + i_ * 256;                                         \
        load_lds16(vg_ + (size_t)(ch_ + lane) * 8, &V_lds[ch_ * 8]);         \
    }                                                                        \
} while (0)

#define LOADMR3(mr, ktt) do {                                                \
    _Pragma("unroll") for (int r_ = 0; r_ < 4; r_++)                         \
        mr[r_] = mb[r_ * NKT + (ktt)];                                       \
} while (0)

#define STEP3(mrC, mrN, t, tn) do {                                          \
    __syncthreads();                   /* publishes K(t); V/P reads done */  \
    STAGE_V3(t);                                                             \
    LOADMR3(mrN, (tn));                                                      \
    /* ---- QK ---- */                                                       \
    f32x4 s[4];                                                              \
    _Pragma("unroll") for (int nb = 0; nb < 4; nb++)                         \
        s[nb] = (f32x4){0.f, 0.f, 0.f, 0.f};                                 \
    __builtin_amdgcn_s_setprio(1);                                           \
    _Pragma("unroll") for (int nb = 0; nb < 4; nb++) {                       \
        bf16x8 bk[4];                                                        \
        _Pragma("unroll") for (int ks = 0; ks < 4; ks++)                     \
            bk[ks] = *(const bf16x8*)&K_lds[ks * 2048 + nb * 512 + c * 32 + swz8]; \
        _Pragma("unroll") for (int ks = 0; ks < 4; ks++)                     \
            s[nb] = __builtin_amdgcn_mfma_f32_16x16x32_bf16(aq[ks], bk[ks], s[nb], 0, 0, 0); \
    }                                                                        \
    __builtin_amdgcn_s_setprio(0);                                           \
    __syncthreads();                   /* publishes V(t); K reads done */    \
    STAGE_K3((tn));                    /* K for next step, same buffer */    \
    /* ---- softmax + P write (wave-private slice) ---- */                   \
    _Pragma("unroll") for (int r = 0; r < 4; r++) {                          \
        unsigned long long bits = mrC[r];                                    \
        unsigned wlo = (unsigned)(bits >> c);                                \
        unsigned whi = (unsigned)(bits >> 32) >> c;                          \
        _Pragma("unroll") for (int nbp = 0; nbp < 2; nbp++) {                \
            unsigned wb = nbp ? whi : wlo;                                   \
            float p0 = fexp2(fmaf(s[2 * nbp][r],     SCALE2, NSHIFT2));      \
            float p1 = fexp2(fmaf(s[2 * nbp + 1][r], SCALE2, NSHIFT2));      \
            if (wb & 1u)       p0 = 0.0f;                                    \
            if (wb & 0x10000u) p1 = 0.0f;                                    \
            l[r] += p0 + p1;                                                 \
            unsigned pk = cvtpk(p0, p1);                                     \
            int base = nbp * 512 + quad * 128 + r * 32 + (c & 7);            \
            Pw[base + ((0 + (c >> 3)) ^ quad) * 8] = (unsigned short)pk;     \
            Pw[base + ((2 + (c >> 3)) ^ quad) * 8] = (unsigned short)(pk >> 16); \
        }                                                                    \
    }                                                                        \
    /* ---- PV ---- */                                                       \
    bf16x8 ap[2];                                                            \
    _Pragma("unroll") for (int ks2 = 0; ks2 < 2; ks2++)                      \
        ap[ks2] = *(const bf16x8*)&Pw[ks2 * 512 + c * 32 + ((quad ^ (c >> 2)) * 8)]; \
    __builtin_amdgcn_s_setprio(1);                                           \
    _Pragma("unroll") for (int nb = 0; nb < 8; nb++) {                       \
        bf16x8 bv0 = *(const bf16x8*)&V_lds[nb * 512 + c * 32 + swz8];       \
        bf16x8 bv1 = *(const bf16x8*)&V_lds[4096 + nb * 512 + c * 32 + swz8]; \
        oa[nb] = __builtin_amdgcn_mfma_f32_16x16x32_bf16(ap[0], bv0, oa[nb], 0, 0, 0); \
        oa[nb] = __builtin_amdgcn_mfma_f32_16x16x32_bf16(ap[1], bv1, oa[nb], 0, 0, 0); \
    }                                                                        \
    __builtin_amdgcn_s_setprio(0);                                           \
} while (0)

__global__ __launch_bounds__(256, 4)
void fa3(const float* __restrict__ Q, const unsigned short* __restrict__ Kp,
         const unsigned short* __restrict__ Vp, const unsigned long long* __restrict__ MB,
         float* __restrict__ out)
{
    __shared__ __align__(16) unsigned short K_lds[64 * 128];  // 16 KB
    __shared__ __align__(16) unsigned short V_lds[64 * 128];  // 16 KB
    __shared__ __align__(16) unsigned short P_lds[4 * 1024];  // 8 KB (2KB/wave)

    const int tid  = threadIdx.x;
    const int w    = tid >> 6;
    const int lane = tid & 63;
    const int quad = lane >> 4;
    const int c    = lane & 15;
    const int swz8 = (quad ^ ((c >> 1) & 3)) * 8;

    // XCD-aware swizzle: 1024 blocks -> 128 consecutive per XCD = 4 full bh.
    const int bid0 = blockIdx.x;
    const int bid  = ((bid0 & 7) << 7) | (bid0 >> 3);
    const int qt  = bid & 31;
    const int bh  = bid >> 5;
    const int b_i = bh >> 4;
    const int qbase = qt * 64 + w * 16;
    const size_t bh_off = (size_t)bh * DH;

    // Q fragments (A-operand): aq[ks], rows qbase+c
    bf16x8 aq[4];
    {
        const float* qrow = Q + (size_t)(qbase + c) * 4096 + bh_off;
        #pragma unroll
        for (int ks = 0; ks < 4; ks++) {
            const int d0 = ks * 32 + quad * 8;
            float4 f0 = *(const float4*)(qrow + d0);
            float4 f1 = *(const float4*)(qrow + d0 + 4);
            uint4 u;
            u.x = cvtpk(f0.x, f0.y); u.y = cvtpk(f0.z, f0.w);
            u.z = cvtpk(f1.x, f1.y); u.w = cvtpk(f1.z, f1.w);
            aq[ks] = *(bf16x8*)&u;
        }
    }

    f32x4 oa[8];
    #pragma unroll
    for (int nb = 0; nb < 8; nb++) oa[nb] = (f32x4){0.f, 0.f, 0.f, 0.f};
    float l[4];
    #pragma unroll
    for (int r = 0; r < 4; r++) l[r] = 0.0f;

    const unsigned short* KpT = Kp + (size_t)bh * (NKT * 8192);
    const unsigned short* VpT = Vp + (size_t)bh * (NKT * 8192);
    const unsigned long long* mb = MB + (size_t)(b_i * SQ + qbase + quad * 4) * NKT;
    unsigned short* Pw = &P_lds[w * 1024];

    unsigned long long mrA[4], mrB[4];

    // prologue: stage K tile 0 + masks for tile 0
    STAGE_K3(0);
    LOADMR3(mrA, 0);

    for (int kt = 0; kt < NKT; kt += 2) {
        STEP3(mrA, mrB, kt, kt + 1);
        STEP3(mrB, mrA, kt + 1, (kt + 2) & 31);
    }

    // epilogue: reduce l across 16 lanes, 1/l (0 if all masked), store
    #pragma unroll
    for (int r = 0; r < 4; r++) {
        float t = l[r];
        t += __shfl_xor(t, 1, 64);
        t += __shfl_xor(t, 2, 64);
        t += __shfl_xor(t, 4, 64);
        t += __shfl_xor(t, 8, 64);
        float inv = (t > 0.0f) ? (1.0f / t) : 0.0f;
        float* orow = out + (size_t)(qbase + quad * 4 + r) * 4096 + bh_off;
        #pragma unroll
        for (int nb = 0; nb < 8; nb++)
            orow[nb * 16 + c] = oa[nb][r] * inv;
    }
}

// ---------------- fallback if workspace too small (unchanged) ----------------
__global__ __launch_bounds__(256)
void fa_fallback(const float* __restrict__ Q, const float* __restrict__ K,
                 const float* __restrict__ V, const int* __restrict__ mask,
                 float* __restrict__ out)
{
    __shared__ unsigned short K_lds[64 * 136];
    __shared__ unsigned short Vt_lds[128 * 72];
    __shared__ unsigned short P_lds[4 * 16 * 72];
    const int tid = threadIdx.x, w = tid >> 6, lane = tid & 63, quad = lane >> 4, c = lane & 15;
    const int gid = blockIdx.x, qtile = gid & 31, bh = gid >> 5, b_i = bh >> 4;
    const int q0 = qtile * 64 + w * 16;
    const size_t bh_off = (size_t)bh * DH;
    bf16x8 aq[4];
    {
        const float* qrow = Q + (size_t)(q0 + c) * 4096 + bh_off;
        #pragma unroll
        for (int ks = 0; ks < 4; ks++) {
            const int d0 = ks * 32 + quad * 8;
            float4 f0 = *(const float4*)(qrow + d0);
            float4 f1 = *(const float4*)(qrow + d0 + 4);
            bf16x8 a;
            a[0] = (short)f2b(f0.x); a[1] = (short)f2b(f0.y); a[2] = (short)f2b(f0.z); a[3] = (short)f2b(f0.w);
            a[4] = (short)f2b(f1.x); a[5] = (short)f2b(f1.y); a[6] = (short)f2b(f1.z); a[7] = (short)f2b(f1.w);
            aq[ks] = a;
        }
    }
    float m_i[4], l_i[4];
    #pragma unroll
    for (int r = 0; r < 4; r++) { m_i[r] = -INFINITY; l_i[r] = 0.0f; }
    f32x4 o_acc[8];
    #pragma unroll
    for (int nb = 0; nb < 8; nb++) o_acc[nb] = (f32x4){0.f, 0.f, 0.f, 0.f};
    const int srow = tid >> 2, scol = (tid & 3) * 4;
    const int* mbase = mask + (size_t)b_i * SQ * SQ;
    for (int kt = 0; kt < SQ; kt += 64) {
        __syncthreads();
        {
            const float* krow = K + (size_t)(kt + srow) * 4096 + bh_off;
            const float* vrow = V + (size_t)(kt + srow) * 4096 + bh_off;
            #pragma unroll
            for (int j = 0; j < 8; j++) {
                const int d0 = scol + j * 16;
                float4 kf = *(const float4*)(krow + d0);
                unsigned lo = (unsigned)f2b(kf.x) | ((unsigned)f2b(kf.y) << 16);
                unsigned hi = (unsigned)f2b(kf.z) | ((unsigned)f2b(kf.w) << 16);
                *(uint2*)&K_lds[srow * 136 + d0] = make_uint2(lo, hi);
                float4 vf = *(const float4*)(vrow + d0);
                Vt_lds[(d0 + 0) * 72 + srow] = f2b(vf.x);
                Vt_lds[(d0 + 1) * 72 + srow] = f2b(vf.y);
                Vt_lds[(d0 + 2) * 72 + srow] = f2b(vf.z);
                Vt_lds[(d0 + 3) * 72 + srow] = f2b(vf.w);
            }
        }
        __syncthreads();
        f32x4 s[4];
        #pragma unroll
        for (int nb = 0; nb < 4; nb++) s[nb] = (f32x4){0.f, 0.f, 0.f, 0.f};
        #pragma unroll
        for (int nb = 0; nb < 4; nb++)
            #pragma unroll
            for (int ks = 0; ks < 4; ks++) {
                bf16x8 bk = *(const bf16x8*)&K_lds[(nb * 16 + c) * 136 + ks * 32 + quad * 8];
                s[nb] = __builtin_amdgcn_mfma_f32_16x16x32_bf16(aq[ks], bk, s[nb], 0, 0, 0);
            }
        float rowmax[4];
        #pragma unroll
        for (int r = 0; r < 4; r++) rowmax[r] = -INFINITY;
        #pragma unroll
        for (int r = 0; r < 4; r++) {
            const int* mp = mbase + (size_t)(q0 + quad * 4 + r) * SQ + kt + c;
            #pragma unroll
            for (int nb = 0; nb < 4; nb++) {
                float v = s[nb][r] * SCALEF;
                if (mp[nb * 16] != 0) v = -10000.0f;
                s[nb][r] = v;
                rowmax[r] = fmaxf(rowmax[r], v);
            }
        }
        #pragma unroll
        for (int r = 0; r < 4; r++)
            #pragma unroll
            for (int off = 1; off < 16; off <<= 1)
                rowmax[r] = fmaxf(rowmax[r], __shfl_xor(rowmax[r], off, 64));
        float alpha[4], rowsum[4];
        #pragma unroll
        for (int r = 0; r < 4; r++) {
            float mn = fmaxf(m_i[r], rowmax[r]);
            alpha[r] = __expf(m_i[r] - mn);
            m_i[r] = mn;
            rowsum[r] = 0.0f;
        }
        #pragma unroll
        for (int r = 0; r < 4; r++)
            #pragma unroll
            for (int nb = 0; nb < 4; nb++) {
                float p = __expf(s[nb][r] - m_i[r]);
                rowsum[r] += p;
                P_lds[(w * 16 + quad * 4 + r) * 72 + nb * 16 + c] = f2b(p);
            }
        #pragma unroll
        for (int r = 0; r < 4; r++) {
            #pragma unroll
            for (int off = 1; off < 16; off <<= 1)
                rowsum[r] += __shfl_xor(rowsum[r], off, 64);
            l_i[r] = l_i[r] * alpha[r] + rowsum[r];
        }
        #pragma unroll
        for (int nb = 0; nb < 8; nb++)
            #pragma unroll
            for (int r = 0; r < 4; r++) o_acc[nb][r] *= alpha[r];
        bf16x8 ap[2];
        #pragma unroll
        for (int ks = 0; ks < 2; ks++)
            ap[ks] = *(const bf16x8*)&P_lds[(w * 16 + c) * 72 + ks * 32 + quad * 8];
        #pragma unroll
        for (int nb = 0; nb < 8; nb++)
            #pragma unroll
            for (int ks = 0; ks < 2; ks++) {
                bf16x8 bv = *(const bf16x8*)&Vt_lds[(nb * 16 + c) * 72 + ks * 32 + quad * 8];
                o_acc[nb] = __builtin_amdgcn_mfma_f32_16x16x32_bf16(ap[ks], bv, o_acc[nb], 0, 0, 0);
            }
    }
    float inv[4];
    #pragma unroll
    for (int r = 0; r < 4; r++) inv[r] = (m_i[r] > -9999.0f) ? (1.0f / l_i[r]) : 0.0f;
    #pragma unroll
    for (int r = 0; r < 4; r++) {
        float* orow = out + (size_t)(q0 + quad * 4 + r) * 4096 + bh_off;
        #pragma unroll
        for (int nb = 0; nb < 8; nb++) orow[nb * 16 + c] = o_acc[nb][r] * inv[r];
    }
}

extern "C" void kernel_launch(void* const* d_in, const int* in_sizes, int n_in,
                              void* d_out, int out_size, void* d_ws, size_t ws_size,
                              hipStream_t stream) {
    const float* Q    = (const float*)d_in[0];
    const float* K    = (const float*)d_in[1];
    const float* V    = (const float*)d_in[2];
    const int*   mask = (const int*)d_in[3];
    float* out = (float*)d_out;

    const size_t KP_BYTES = (size_t)32 * 32 * 8192 * 2;   // 16 MiB
    const size_t NEED = 2 * KP_BYTES + (size_t)4096 * NKT * 8;
    if (ws_size < NEED) {
        fa_fallback<<<dim3(1024), dim3(256), 0, stream>>>(Q, K, V, mask, out);
        return;
    }
    unsigned short* Kp = (unsigned short*)d_ws;
    unsigned short* Vp = (unsigned short*)((char*)d_ws + KP_BYTES);
    unsigned long long* MB = (unsigned long long*)((char*)d_ws + 2 * KP_BYTES);

    prep_all<<<dim3(6144), dim3(256), 0, stream>>>(K, V, mask, Kp, Vp, MB);
    fa3<<<dim3(1024), dim3(256), 0, stream>>>(Q, Kp, Vp, MB, out);
}

// Round 5
// 280.044 us; speedup vs baseline: 1.4733x; 1.0305x over previous
//
#include <hip/hip_runtime.h>
#include <math.h>

#define SQ   2048
#define DH   128
#define NKT  32            // SQ/64 key tiles
#define SCALEF  0.08838834764831845f   // 1/sqrt(128)  (fallback path)
#define SCALE2  0.12751743f            // (1/sqrt(128)) * log2(e)
#define NSHIFT2 (-23.083121f)          // -16 * log2(e)  (fixed softmax shift, exp2 domain)

typedef __attribute__((ext_vector_type(8))) short bf16x8;
typedef __attribute__((ext_vector_type(4))) float f32x4;

__device__ __forceinline__ unsigned short f2b(float f) {
    unsigned int u = __float_as_uint(f);
    u += 0x7FFFu + ((u >> 16) & 1u);
    return (unsigned short)(u >> 16);
}
// RNE pack of two f32 -> bf16x2 in one VALU op (gfx950)
__device__ __forceinline__ unsigned int cvtpk(float lo, float hi) {
    unsigned int r;
    asm("v_cvt_pk_bf16_f32 %0, %1, %2" : "=v"(r) : "v"(lo), "v"(hi));
    return r;
}
// 2^x via v_exp_f32
__device__ __forceinline__ float fexp2(float x) {
    float r;
    asm("v_exp_f32 %0, %1" : "=v"(r) : "v"(x));
    return r;
}

typedef __attribute__((address_space(1))) const unsigned int guint;
typedef __attribute__((address_space(3))) unsigned int luint;
__device__ __forceinline__ void load_lds16(const void* g, void* l) {
    __builtin_amdgcn_global_load_lds((guint*)g, (luint*)l, 16, 0, 0);
}

// ---------------- LAYOUTS (bank-conflict-swizzled, validated R2v2) ----------
// K tile (bh,kt): chunk id = (ks*64+key)*4+q', content K[key][ks*32+(q'^((key>>1)&3))*8+j]
// V tile (bh,kt): chunk id = (ks2*128+d)*4+q', content V[ks2*32+(q'^((d>>1)&3))*8+j][d]
// Reader with (quad,c) uses slot q' = quad ^ ((c>>1)&3).

// ---------------- prep (validated R2 two-dispatch form) ----------------
__device__ __forceinline__ void prep_k_piece(const float* __restrict__ K,
                                             unsigned short* __restrict__ Kp, int id)
{
    int quad = id & 3;
    int key  = (id >> 2) & 63;
    int ks   = (id >> 8) & 3;
    int kt   = (id >> 10) & 31;
    int bh   = id >> 15;
    int qsrc = quad ^ ((key >> 1) & 3);
    const float* src = K + (size_t)(kt * 64 + key) * 4096 + bh * DH + ks * 32 + qsrc * 8;
    float4 f0 = *(const float4*)src;
    float4 f1 = *(const float4*)(src + 4);
    uint4 o;
    o.x = cvtpk(f0.x, f0.y); o.y = cvtpk(f0.z, f0.w);
    o.z = cvtpk(f1.x, f1.y); o.w = cvtpk(f1.z, f1.w);
    *(uint4*)(Kp + (size_t)id * 8) = o;
}

__device__ __forceinline__ void prep_v_piece(const float* __restrict__ V,
                                             unsigned short* __restrict__ Vp,
                                             int t, int tid)
{
    int kt   = t & 31, bh = t >> 5;
    int quad = tid & 3;
    int d2   = tid >> 2;                // 0..63
    int s    = (d2 >> 1) & 3;
    int rb   = (quad ^ s) * 8;
    unsigned short* ob = Vp + (size_t)t * 8192;
    #pragma unroll
    for (int ks2 = 0; ks2 < 2; ks2++) {
        #pragma unroll
        for (int dhi = 0; dhi < 2; dhi++) {
            int d = dhi * 64 + d2;
            const float* vb = V + (size_t)(kt * 64 + ks2 * 32 + rb) * 4096 + bh * DH + d;
            float f[8];
            #pragma unroll
            for (int j = 0; j < 8; j++)
                f[j] = vb[(size_t)j * 4096];
            uint4 o;
            o.x = cvtpk(f[0], f[1]); o.y = cvtpk(f[2], f[3]);
            o.z = cvtpk(f[4], f[5]); o.w = cvtpk(f[6], f[7]);
            *(uint4*)(ob + ((size_t)(ks2 * 128 + d) * 4 + quad) * 8) = o;
        }
    }
}

__device__ __forceinline__ void prep_m_piece(const int* __restrict__ M,
                                             unsigned long long* __restrict__ B,
                                             int b2, int tid)
{
    int wid  = b2 * 4 + (tid >> 6);     // row in [0,4096)
    int lane = tid & 63;
    const int* src = M + (size_t)wid * SQ + lane;
    unsigned long long* dst = B + (size_t)wid * NKT;
    #pragma unroll
    for (int t = 0; t < NKT; t++) {
        unsigned long long bm = __ballot(src[t * 64] != 0);
        if (lane == 0) dst[t] = bm;
    }
}

__global__ __launch_bounds__(256)
void prep_all(const float* __restrict__ K, const float* __restrict__ V,
              const int* __restrict__ M,
              unsigned short* __restrict__ Kp, unsigned short* __restrict__ Vp,
              unsigned long long* __restrict__ B)
{
    const int bid = blockIdx.x;
    const int tid = threadIdx.x;
    if (bid < 4096)       prep_k_piece(K, Kp, bid * 256 + tid);
    else if (bid < 5120)  prep_v_piece(V, Vp, bid - 4096, tid);
    else                  prep_m_piece(M, B, bid - 5120, tid);
}

// ---------------- fa3: high-occupancy attention ----------------
// 1024 blocks x 256 thr, 16 q-rows/wave, LDS 40KB -> 4 blocks/CU (16 waves/CU).
// launch_bounds(256,2): R4's (256,4) drove the allocator to a 64-VGPR target
// -> scratch spills (+85MB write-through HBM traffic). (256,2) is the proven
// setting (fa2: 124-128 VGPR, no spills); fa3's pressure is lower still.
// Pipeline per step (2 __syncthreads, no counted vmcnt):
//   bar0 (implicit vmcnt0 publishes K(t) DMA'd mid-previous step)
//   STAGE_V(t) + LOADMR(t+1)      <- V hides under QK
//   QK(t)
//   bar1 (implicit vmcnt0 publishes V(t); guarantees K reads done)
//   STAGE_K(t+1)                  <- K hides under softmax+PV
//   softmax(t) -> P (wave-private LDS slice) -> PV(t)

#define STAGE_K3(ktt) do {                                                   \
    const unsigned short* kg_ = KpT + (size_t)(ktt) * 8192;                  \
    _Pragma("unroll") for (int i_ = 0; i_ < 4; i_++) {                       \
        int ch_ = w * 64 + i_ * 256;                                         \
        load_lds16(kg_ + (size_t)(ch_ + lane) * 8, &K_lds[ch_ * 8]);         \
    }                                                                        \
} while (0)

#define STAGE_V3(ktt) do {                                                   \
    const unsigned short* vg_ = VpT + (size_t)(ktt) * 8192;                  \
    _Pragma("unroll") for (int i_ = 0; i_ < 4; i_++) {                       \
        int ch_ = w * 64 + i_ * 256;                                         \
        load_lds16(vg_ + (size_t)(ch_ + lane) * 8, &V_lds[ch_ * 8]);         \
    }                                                                        \
} while (0)

#define LOADMR3(mr, ktt) do {                                                \
    _Pragma("unroll") for (int r_ = 0; r_ < 4; r_++)                         \
        mr[r_] = mb[r_ * NKT + (ktt)];                                       \
} while (0)

#define STEP3(mrC, mrN, t, tn) do {                                          \
    __syncthreads();                   /* publishes K(t); V/P reads done */  \
    STAGE_V3(t);                                                             \
    LOADMR3(mrN, (tn));                                                      \
    /* ---- QK ---- */                                                       \
    f32x4 s[4];                                                              \
    _Pragma("unroll") for (int nb = 0; nb < 4; nb++)                         \
        s[nb] = (f32x4){0.f, 0.f, 0.f, 0.f};                                 \
    __builtin_amdgcn_s_setprio(1);                                           \
    _Pragma("unroll") for (int nb = 0; nb < 4; nb++) {                       \
        bf16x8 bk[4];                                                        \
        _Pragma("unroll") for (int ks = 0; ks < 4; ks++)                     \
            bk[ks] = *(const bf16x8*)&K_lds[ks * 2048 + nb * 512 + c * 32 + swz8]; \
        _Pragma("unroll") for (int ks = 0; ks < 4; ks++)                     \
            s[nb] = __builtin_amdgcn_mfma_f32_16x16x32_bf16(aq[ks], bk[ks], s[nb], 0, 0, 0); \
    }                                                                        \
    __builtin_amdgcn_s_setprio(0);                                           \
    __syncthreads();                   /* publishes V(t); K reads done */    \
    STAGE_K3((tn));                    /* K for next step, same buffer */    \
    /* ---- softmax + P write (wave-private slice) ---- */                   \
    _Pragma("unroll") for (int r = 0; r < 4; r++) {                          \
        unsigned long long bits = mrC[r];                                    \
        unsigned wlo = (unsigned)(bits >> c);                                \
        unsigned whi = (unsigned)(bits >> 32) >> c;                          \
        _Pragma("unroll") for (int nbp = 0; nbp < 2; nbp++) {                \
            unsigned wb = nbp ? whi : wlo;                                   \
            float p0 = fexp2(fmaf(s[2 * nbp][r],     SCALE2, NSHIFT2));      \
            float p1 = fexp2(fmaf(s[2 * nbp + 1][r], SCALE2, NSHIFT2));      \
            if (wb & 1u)       p0 = 0.0f;                                    \
            if (wb & 0x10000u) p1 = 0.0f;                                    \
            l[r] += p0 + p1;                                                 \
            unsigned pk = cvtpk(p0, p1);                                     \
            int base = nbp * 512 + quad * 128 + r * 32 + (c & 7);            \
            Pw[base + ((0 + (c >> 3)) ^ quad) * 8] = (unsigned short)pk;     \
            Pw[base + ((2 + (c >> 3)) ^ quad) * 8] = (unsigned short)(pk >> 16); \
        }                                                                    \
    }                                                                        \
    /* ---- PV ---- */                                                       \
    bf16x8 ap[2];                                                            \
    _Pragma("unroll") for (int ks2 = 0; ks2 < 2; ks2++)                      \
        ap[ks2] = *(const bf16x8*)&Pw[ks2 * 512 + c * 32 + ((quad ^ (c >> 2)) * 8)]; \
    __builtin_amdgcn_s_setprio(1);                                           \
    _Pragma("unroll") for (int nb = 0; nb < 8; nb++) {                       \
        bf16x8 bv0 = *(const bf16x8*)&V_lds[nb * 512 + c * 32 + swz8];       \
        bf16x8 bv1 = *(const bf16x8*)&V_lds[4096 + nb * 512 + c * 32 + swz8]; \
        oa[nb] = __builtin_amdgcn_mfma_f32_16x16x32_bf16(ap[0], bv0, oa[nb], 0, 0, 0); \
        oa[nb] = __builtin_amdgcn_mfma_f32_16x16x32_bf16(ap[1], bv1, oa[nb], 0, 0, 0); \
    }                                                                        \
    __builtin_amdgcn_s_setprio(0);                                           \
} while (0)

__global__ __launch_bounds__(256, 2)
void fa3(const float* __restrict__ Q, const unsigned short* __restrict__ Kp,
         const unsigned short* __restrict__ Vp, const unsigned long long* __restrict__ MB,
         float* __restrict__ out)
{
    __shared__ __align__(16) unsigned short K_lds[64 * 128];  // 16 KB
    __shared__ __align__(16) unsigned short V_lds[64 * 128];  // 16 KB
    __shared__ __align__(16) unsigned short P_lds[4 * 1024];  // 8 KB (2KB/wave)

    const int tid  = threadIdx.x;
    const int w    = tid >> 6;
    const int lane = tid & 63;
    const int quad = lane >> 4;
    const int c    = lane & 15;
    const int swz8 = (quad ^ ((c >> 1) & 3)) * 8;

    // XCD-aware swizzle: 1024 blocks -> 128 consecutive per XCD = 4 full bh.
    const int bid0 = blockIdx.x;
    const int bid  = ((bid0 & 7) << 7) | (bid0 >> 3);
    const int qt  = bid & 31;
    const int bh  = bid >> 5;
    const int b_i = bh >> 4;
    const int qbase = qt * 64 + w * 16;
    const size_t bh_off = (size_t)bh * DH;

    // Q fragments (A-operand): aq[ks], rows qbase+c
    bf16x8 aq[4];
    {
        const float* qrow = Q + (size_t)(qbase + c) * 4096 + bh_off;
        #pragma unroll
        for (int ks = 0; ks < 4; ks++) {
            const int d0 = ks * 32 + quad * 8;
            float4 f0 = *(const float4*)(qrow + d0);
            float4 f1 = *(const float4*)(qrow + d0 + 4);
            uint4 u;
            u.x = cvtpk(f0.x, f0.y); u.y = cvtpk(f0.z, f0.w);
            u.z = cvtpk(f1.x, f1.y); u.w = cvtpk(f1.z, f1.w);
            aq[ks] = *(bf16x8*)&u;
        }
    }

    f32x4 oa[8];
    #pragma unroll
    for (int nb = 0; nb < 8; nb++) oa[nb] = (f32x4){0.f, 0.f, 0.f, 0.f};
    float l[4];
    #pragma unroll
    for (int r = 0; r < 4; r++) l[r] = 0.0f;

    const unsigned short* KpT = Kp + (size_t)bh * (NKT * 8192);
    const unsigned short* VpT = Vp + (size_t)bh * (NKT * 8192);
    const unsigned long long* mb = MB + (size_t)(b_i * SQ + qbase + quad * 4) * NKT;
    unsigned short* Pw = &P_lds[w * 1024];

    unsigned long long mrA[4], mrB[4];

    // prologue: stage K tile 0 + masks for tile 0
    STAGE_K3(0);
    LOADMR3(mrA, 0);

    for (int kt = 0; kt < NKT; kt += 2) {
        STEP3(mrA, mrB, kt, kt + 1);
        STEP3(mrB, mrA, kt + 1, (kt + 2) & 31);
    }

    // epilogue: reduce l across 16 lanes, 1/l (0 if all masked), store
    #pragma unroll
    for (int r = 0; r < 4; r++) {
        float t = l[r];
        t += __shfl_xor(t, 1, 64);
        t += __shfl_xor(t, 2, 64);
        t += __shfl_xor(t, 4, 64);
        t += __shfl_xor(t, 8, 64);
        float inv = (t > 0.0f) ? (1.0f / t) : 0.0f;
        float* orow = out + (size_t)(qbase + quad * 4 + r) * 4096 + bh_off;
        #pragma unroll
        for (int nb = 0; nb < 8; nb++)
            orow[nb * 16 + c] = oa[nb][r] * inv;
    }
}

// ---------------- fallback if workspace too small (unchanged) ----------------
__global__ __launch_bounds__(256)
void fa_fallback(const float* __restrict__ Q, const float* __restrict__ K,
                 const float* __restrict__ V, const int* __restrict__ mask,
                 float* __restrict__ out)
{
    __shared__ unsigned short K_lds[64 * 136];
    __shared__ unsigned short Vt_lds[128 * 72];
    __shared__ unsigned short P_lds[4 * 16 * 72];
    const int tid = threadIdx.x, w = tid >> 6, lane = tid & 63, quad = lane >> 4, c = lane & 15;
    const int gid = blockIdx.x, qtile = gid & 31, bh = gid >> 5, b_i = bh >> 4;
    const int q0 = qtile * 64 + w * 16;
    const size_t bh_off = (size_t)bh * DH;
    bf16x8 aq[4];
    {
        const float* qrow = Q + (size_t)(q0 + c) * 4096 + bh_off;
        #pragma unroll
        for (int ks = 0; ks < 4; ks++) {
            const int d0 = ks * 32 + quad * 8;
            float4 f0 = *(const float4*)(qrow + d0);
            float4 f1 = *(const float4*)(qrow + d0 + 4);
            bf16x8 a;
            a[0] = (short)f2b(f0.x); a[1] = (short)f2b(f0.y); a[2] = (short)f2b(f0.z); a[3] = (short)f2b(f0.w);
            a[4] = (short)f2b(f1.x); a[5] = (short)f2b(f1.y); a[6] = (short)f2b(f1.z); a[7] = (short)f2b(f1.w);
            aq[ks] = a;
        }
    }
    float m_i[4], l_i[4];
    #pragma unroll
    for (int r = 0; r < 4; r++) { m_i[r] = -INFINITY; l_i[r] = 0.0f; }
    f32x4 o_acc[8];
    #pragma unroll
    for (int nb = 0; nb < 8; nb++) o_acc[nb] = (f32x4){0.f, 0.f, 0.f, 0.f};
    const int srow = tid >> 2, scol = (tid & 3) * 4;
    const int* mbase = mask + (size_t)b_i * SQ * SQ;
    for (int kt = 0; kt < SQ; kt += 64) {
        __syncthreads();
        {
            const float* krow = K + (size_t)(kt + srow) * 4096 + bh_off;
            const float* vrow = V + (size_t)(kt + srow) * 4096 + bh_off;
            #pragma unroll
            for (int j = 0; j < 8; j++) {
                const int d0 = scol + j * 16;
                float4 kf = *(const float4*)(krow + d0);
                unsigned lo = (unsigned)f2b(kf.x) | ((unsigned)f2b(kf.y) << 16);
                unsigned hi = (unsigned)f2b(kf.z) | ((unsigned)f2b(kf.w) << 16);
                *(uint2*)&K_lds[srow * 136 + d0] = make_uint2(lo, hi);
                float4 vf = *(const float4*)(vrow + d0);
                Vt_lds[(d0 + 0) * 72 + srow] = f2b(vf.x);
                Vt_lds[(d0 + 1) * 72 + srow] = f2b(vf.y);
                Vt_lds[(d0 + 2) * 72 + srow] = f2b(vf.z);
                Vt_lds[(d0 + 3) * 72 + srow] = f2b(vf.w);
            }
        }
        __syncthreads();
        f32x4 s[4];
        #pragma unroll
        for (int nb = 0; nb < 4; nb++) s[nb] = (f32x4){0.f, 0.f, 0.f, 0.f};
        #pragma unroll
        for (int nb = 0; nb < 4; nb++)
            #pragma unroll
            for (int ks = 0; ks < 4; ks++) {
                bf16x8 bk = *(const bf16x8*)&K_lds[(nb * 16 + c) * 136 + ks * 32 + quad * 8];
                s[nb] = __builtin_amdgcn_mfma_f32_16x16x32_bf16(aq[ks], bk, s[nb], 0, 0, 0);
            }
        float rowmax[4];
        #pragma unroll
        for (int r = 0; r < 4; r++) rowmax[r] = -INFINITY;
        #pragma unroll
        for (int r = 0; r < 4; r++) {
            const int* mp = mbase + (size_t)(q0 + quad * 4 + r) * SQ + kt + c;
            #pragma unroll
            for (int nb = 0; nb < 4; nb++) {
                float v = s[nb][r] * SCALEF;
                if (mp[nb * 16] != 0) v = -10000.0f;
                s[nb][r] = v;
                rowmax[r] = fmaxf(rowmax[r], v);
            }
        }
        #pragma unroll
        for (int r = 0; r < 4; r++)
            #pragma unroll
            for (int off = 1; off < 16; off <<= 1)
                rowmax[r] = fmaxf(rowmax[r], __shfl_xor(rowmax[r], off, 64));
        float alpha[4], rowsum[4];
        #pragma unroll
        for (int r = 0; r < 4; r++) {
            float mn = fmaxf(m_i[r], rowmax[r]);
            alpha[r] = __expf(m_i[r] - mn);
            m_i[r] = mn;
            rowsum[r] = 0.0f;
        }
        #pragma unroll
        for (int r = 0; r < 4; r++)
            #pragma unroll
            for (int nb = 0; nb < 4; nb++) {
                float p = __expf(s[nb][r] - m_i[r]);
                rowsum[r] += p;
                P_lds[(w * 16 + quad * 4 + r) * 72 + nb * 16 + c] = f2b(p);
            }
        #pragma unroll
        for (int r = 0; r < 4; r++) {
            #pragma unroll
            for (int off = 1; off < 16; off <<= 1)
                rowsum[r] += __shfl_xor(rowsum[r], off, 64);
            l_i[r] = l_i[r] * alpha[r] + rowsum[r];
        }
        #pragma unroll
        for (int nb = 0; nb < 8; nb++)
            #pragma unroll
            for (int r = 0; r < 4; r++) o_acc[nb][r] *= alpha[r];
        bf16x8 ap[2];
        #pragma unroll
        for (int ks = 0; ks < 2; ks++)
            ap[ks] = *(const bf16x8*)&P_lds[(w * 16 + c) * 72 + ks * 32 + quad * 8];
        #pragma unroll
        for (int nb = 0; nb < 8; nb++)
            #pragma unroll
            for (int ks = 0; ks < 2; ks++) {
                bf16x8 bv = *(const bf16x8*)&Vt_lds[(nb * 16 + c) * 72 + ks * 32 + quad * 8];
                o_acc[nb] = __builtin_amdgcn_mfma_f32_16x16x32_bf16(ap[ks], bv, o_acc[nb], 0, 0, 0);
            }
    }
    float inv[4];
    #pragma unroll
    for (int r = 0; r < 4; r++) inv[r] = (m_i[r] > -9999.0f) ? (1.0f / l_i[r]) : 0.0f;
    #pragma unroll
    for (int r = 0; r < 4; r++) {
        float* orow = out + (size_t)(q0 + quad * 4 + r) * 4096 + bh_off;
        #pragma unroll
        for (int nb = 0; nb < 8; nb++) orow[nb * 16 + c] = o_acc[nb][r] * inv[r];
    }
}

extern "C" void kernel_launch(void* const* d_in, const int* in_sizes, int n_in,
                              void* d_out, int out_size, void* d_ws, size_t ws_size,
                              hipStream_t stream) {
    const float* Q    = (const float*)d_in[0];
    const float* K    = (const float*)d_in[1];
    const float* V    = (const float*)d_in[2];
    const int*   mask = (const int*)d_in[3];
    float* out = (float*)d_out;

    const size_t KP_BYTES = (size_t)32 * 32 * 8192 * 2;   // 16 MiB
    const size_t NEED = 2 * KP_BYTES + (size_t)4096 * NKT * 8;
    if (ws_size < NEED) {
        fa_fallback<<<dim3(1024), dim3(256), 0, stream>>>(Q, K, V, mask, out);
        return;
    }
    unsigned short* Kp = (unsigned short*)d_ws;
    unsigned short* Vp = (unsigned short*)((char*)d_ws + KP_BYTES);
    unsigned long long* MB = (unsigned long long*)((char*)d_ws + 2 * KP_BYTES);

    prep_all<<<dim3(6144), dim3(256), 0, stream>>>(K, V, mask, Kp, Vp, MB);
    fa3<<<dim3(1024), dim3(256), 0, stream>>>(Q, Kp, Vp, MB, out);
}

// Round 6
// 262.735 us; speedup vs baseline: 1.5704x; 1.0659x over previous
//
#include <hip/hip_runtime.h>
#include <math.h>

#define SQ   2048
#define DH   128
#define NKT  32            // SQ/64 key tiles
#define SCALEF  0.08838834764831845f   // 1/sqrt(128)  (fallback path)
#define SCALE2  0.12751743f            // (1/sqrt(128)) * log2(e)
#define NSHIFT2 (-23.083121f)          // -16 * log2(e)  (fixed softmax shift, exp2 domain)

typedef __attribute__((ext_vector_type(8))) short bf16x8;
typedef __attribute__((ext_vector_type(4))) float f32x4;

__device__ __forceinline__ unsigned short f2b(float f) {
    unsigned int u = __float_as_uint(f);
    u += 0x7FFFu + ((u >> 16) & 1u);
    return (unsigned short)(u >> 16);
}
// RNE pack of two f32 -> bf16x2 in one VALU op (gfx950)
__device__ __forceinline__ unsigned int cvtpk(float lo, float hi) {
    unsigned int r;
    asm("v_cvt_pk_bf16_f32 %0, %1, %2" : "=v"(r) : "v"(lo), "v"(hi));
    return r;
}
// 2^x via v_exp_f32
__device__ __forceinline__ float fexp2(float x) {
    float r;
    asm("v_exp_f32 %0, %1" : "=v"(r) : "v"(x));
    return r;
}

typedef __attribute__((address_space(1))) const unsigned int guint;
typedef __attribute__((address_space(3))) unsigned int luint;
__device__ __forceinline__ void load_lds16(const void* g, void* l) {
    __builtin_amdgcn_global_load_lds((guint*)g, (luint*)l, 16, 0, 0);
}

// ---------------- LAYOUTS (bank-conflict-swizzled, validated R2v2) ----------
// K tile (bh,kt): chunk id = (ks*64+key)*4+q', content K[key][ks*32+(q'^((key>>1)&3))*8+j]
// V tile (bh,kt): chunk id = (ks2*128+d)*4+q', content V[ks2*32+(q'^((d>>1)&3))*8+j][d]
// Reader with (quad,c) uses slot q' = quad ^ ((c>>1)&3).

// ---------------- fused pre-pass (one dispatch, V split for balance) --------
// blocks [0,4096):     K -> bf16 chunk layout (swizzled slot)   1 uint4/thr
// blocks [4096,6144):  V -> transposed chunk layout; dhi is a block coord so
//                      per-block work (2 uint4/thr) ~matches K blocks (tail fix)
// blocks [6144,7168):  mask int32 -> u64 bitmasks
__global__ __launch_bounds__(256)
void prep_all(const float* __restrict__ K, const float* __restrict__ V,
              const int* __restrict__ M,
              unsigned short* __restrict__ Kp, unsigned short* __restrict__ Vp,
              unsigned long long* __restrict__ B)
{
    const int bid = blockIdx.x;
    const int tid = threadIdx.x;
    if (bid < 4096) {                       // ---- K part ----
        int id   = bid * 256 + tid;
        int quad = id & 3;
        int key  = (id >> 2) & 63;
        int ks   = (id >> 8) & 3;
        int kt   = (id >> 10) & 31;
        int bh   = id >> 15;
        int qsrc = quad ^ ((key >> 1) & 3);     // swizzled slot content
        const float* src = K + (size_t)(kt * 64 + key) * 4096 + bh * DH + ks * 32 + qsrc * 8;
        float4 f0 = *(const float4*)src;
        float4 f1 = *(const float4*)(src + 4);
        uint4 o;
        o.x = cvtpk(f0.x, f0.y); o.y = cvtpk(f0.z, f0.w);
        o.z = cvtpk(f1.x, f1.y); o.w = cvtpk(f1.z, f1.w);
        *(uint4*)(Kp + (size_t)id * 8) = o;
    } else if (bid < 6144) {                // ---- V part: register transpose ----
        int b2   = bid - 4096;
        int t    = b2 >> 1;                 // tile = bh*32+kt
        int dhi  = b2 & 1;                  // d-half (block coord: load balance)
        int kt   = t & 31, bh = t >> 5;
        int quad = tid & 3;
        int d2   = tid >> 2;                // 0..63
        int s    = (d2 >> 1) & 3;           // == ((d>>1)&3), dhi-invariant
        int rb   = (quad ^ s) * 8;          // row-block within 32-key half
        int d    = dhi * 64 + d2;
        unsigned short* ob = Vp + (size_t)t * 8192;
        #pragma unroll
        for (int ks2 = 0; ks2 < 2; ks2++) {
            const float* vb = V + (size_t)(kt * 64 + ks2 * 32 + rb) * 4096 + bh * DH + d;
            float f[8];
            #pragma unroll
            for (int j = 0; j < 8; j++)
                f[j] = vb[(size_t)j * 4096];
            uint4 o;
            o.x = cvtpk(f[0], f[1]); o.y = cvtpk(f[2], f[3]);
            o.z = cvtpk(f[4], f[5]); o.w = cvtpk(f[6], f[7]);
            // chunk = (ks2*128+d)*4+quad -> contiguous within (ks2,dhi) group
            *(uint4*)(ob + ((size_t)(ks2 * 128 + d) * 4 + quad) * 8) = o;
        }
    } else {                                // ---- mask part ----
        int b2   = bid - 6144;
        int wid  = b2 * 4 + (tid >> 6);     // row in [0,4096)
        int lane = tid & 63;
        const int* src = M + (size_t)wid * SQ + lane;
        unsigned long long* dst = B + (size_t)wid * NKT;
        #pragma unroll
        for (int t = 0; t < NKT; t++) {
            unsigned long long bm = __ballot(src[t * 64] != 0);
            if (lane == 0) dst[t] = bm;
        }
    }
}

// ---------------- main attention: R2-exact (session best: 119.5us) ----------
#define STAGE(Kl, Vl, ktt) do {                                              \
    const unsigned short* kg_ = KpT + (size_t)(ktt) * 8192;                  \
    const unsigned short* vg_ = VpT + (size_t)(ktt) * 8192;                  \
    _Pragma("unroll") for (int i_ = 0; i_ < 4; i_++) {                       \
        int ch_ = w * 64 + i_ * 256;                                         \
        load_lds16(kg_ + (size_t)(ch_ + lane) * 8, &Kl[ch_ * 8]);            \
    }                                                                        \
    _Pragma("unroll") for (int i_ = 0; i_ < 4; i_++) {                       \
        int ch_ = w * 64 + i_ * 256;                                         \
        load_lds16(vg_ + (size_t)(ch_ + lane) * 8, &Vl[ch_ * 8]);            \
    }                                                                        \
} while (0)

#define LOADMR(mr, ktt) do {                                                 \
    _Pragma("unroll") for (int r_ = 0; r_ < 4; r_++) {                       \
        mr[0][r_] = mb0[r_ * NKT + (ktt)];                                   \
        mr[1][r_] = mb1[r_ * NKT + (ktt)];                                   \
    }                                                                        \
} while (0)

#define COMPUTE(Kl, Vl, mr) do {                                             \
    f32x4 s[2][4];                                                           \
    _Pragma("unroll") for (int blk = 0; blk < 2; blk++)                      \
        _Pragma("unroll") for (int nb = 0; nb < 4; nb++)                     \
            s[blk][nb] = (f32x4){0.f, 0.f, 0.f, 0.f};                        \
    __builtin_amdgcn_s_setprio(1);                                           \
    _Pragma("unroll") for (int nb = 0; nb < 4; nb++) {                       \
        bf16x8 bk[4];                                                        \
        _Pragma("unroll") for (int ks = 0; ks < 4; ks++)                     \
            bk[ks] = *(const bf16x8*)&Kl[ks * 2048 + nb * 512 + c * 32 + swz8]; \
        _Pragma("unroll") for (int blk = 0; blk < 2; blk++)                  \
            _Pragma("unroll") for (int ks = 0; ks < 4; ks++)                 \
                s[blk][nb] = __builtin_amdgcn_mfma_f32_16x16x32_bf16(aq[blk][ks], bk[ks], s[blk][nb], 0, 0, 0); \
    }                                                                        \
    __builtin_amdgcn_s_setprio(0);                                           \
    _Pragma("unroll") for (int blk = 0; blk < 2; blk++) {                    \
        _Pragma("unroll") for (int r = 0; r < 4; r++) {                      \
            unsigned long long bits = mr[blk][r];                            \
            unsigned wlo = (unsigned)(bits >> c);                            \
            unsigned whi = (unsigned)(bits >> 32) >> c;                      \
            _Pragma("unroll") for (int nbp = 0; nbp < 2; nbp++) {            \
                unsigned wb = nbp ? whi : wlo;                               \
                float p0 = fexp2(fmaf(s[blk][2 * nbp][r],     SCALE2, NSHIFT2)); \
                float p1 = fexp2(fmaf(s[blk][2 * nbp + 1][r], SCALE2, NSHIFT2)); \
                if (wb & 1u)       p0 = 0.0f;                                \
                if (wb & 0x10000u) p1 = 0.0f;                                \
                l[blk][r] += p0 + p1;                                        \
                unsigned pk = cvtpk(p0, p1);                                 \
                int base = nbp * 1024 + blk * 512 + quad * 128 + r * 32 + (c & 7); \
                Pw[base + ((0 + (c >> 3)) ^ quad) * 8] = (unsigned short)pk; \
                Pw[base + ((2 + (c >> 3)) ^ quad) * 8] = (unsigned short)(pk >> 16); \
            }                                                                \
        }                                                                    \
    }                                                                        \
    bf16x8 ap[2][2];                                                         \
    _Pragma("unroll") for (int blk = 0; blk < 2; blk++)                      \
        _Pragma("unroll") for (int ks2 = 0; ks2 < 2; ks2++)                  \
            ap[blk][ks2] = *(const bf16x8*)&Pw[ks2 * 1024 + blk * 512 + c * 32 + ((quad ^ (c >> 2)) * 8)]; \
    __builtin_amdgcn_s_setprio(1);                                           \
    _Pragma("unroll") for (int nb = 0; nb < 8; nb++) {                       \
        bf16x8 bv0 = *(const bf16x8*)&Vl[nb * 512 + c * 32 + swz8];          \
        bf16x8 bv1 = *(const bf16x8*)&Vl[4096 + nb * 512 + c * 32 + swz8];   \
        _Pragma("unroll") for (int blk = 0; blk < 2; blk++) {                \
            oa[blk][nb] = __builtin_amdgcn_mfma_f32_16x16x32_bf16(ap[blk][0], bv0, oa[blk][nb], 0, 0, 0); \
            oa[blk][nb] = __builtin_amdgcn_mfma_f32_16x16x32_bf16(ap[blk][1], bv1, oa[blk][nb], 0, 0, 0); \
        }                                                                    \
    }                                                                        \
    __builtin_amdgcn_s_setprio(0);                                           \
} while (0)

// One pipeline step: barA | stage nxt + prefetch next mask rows | counted
// vmcnt(16) (= 8 nxt DMAs + 8 nxt mask loads stay in flight; cur's 8+8 are
// drained) | barB | compute(cur).  Raw barriers: no implicit vmcnt(0) drain.
// NOTE: masks MUST be prefetched with the stage phase — loading them inside
// COMPUTE would make them the youngest vmem ops, and the compiler's wait
// before their use would drain the K/V prefetch DMAs (vmcnt(0)) too.
#define PIPE_STEP(Kc, Vc, mrC, Kn, Vn, mrN, ktn) do {                        \
    __builtin_amdgcn_s_barrier();                                            \
    STAGE(Kn, Vn, (ktn));                                                    \
    LOADMR(mrN, (ktn));                                                      \
    asm volatile("s_waitcnt vmcnt(16)" ::: "memory");                        \
    __builtin_amdgcn_s_barrier();                                            \
    __builtin_amdgcn_sched_barrier(0);                                       \
    COMPUTE(Kc, Vc, mrC);                                                    \
} while (0)

__global__ __launch_bounds__(256, 2)
void fa2(const float* __restrict__ Q, const unsigned short* __restrict__ Kp,
         const unsigned short* __restrict__ Vp, const unsigned long long* __restrict__ MB,
         float* __restrict__ out)
{
    __shared__ __align__(16) unsigned short K_lds[2][64 * 128];  // 2 x 16 KB
    __shared__ __align__(16) unsigned short V_lds[2][64 * 128];  // 2 x 16 KB
    __shared__ __align__(16) unsigned short P_lds[4 * 2048];     // 16 KB

    const int tid  = threadIdx.x;
    const int w    = tid >> 6;
    const int lane = tid & 63;
    const int quad = lane >> 4;
    const int c    = lane & 15;
    // K/V LDS read slot: conflict-light swizzle (2 lanes/bank-group per phase)
    const int swz8 = (quad ^ ((c >> 1) & 3)) * 8;

    // XCD-aware swizzle: each XCD gets 4 full bh groups (64 blocks), so the
    // 16 q-blocks sharing a head's K/V tiles hit the same L2.
    const int bid0 = blockIdx.x;
    const int bid  = ((bid0 & 7) << 6) | (bid0 >> 3);
    const int qt  = bid & 15;
    const int bh  = bid >> 4;
    const int b_i = bh >> 4;
    const int qbase = qt * 128 + w * 32;
    const size_t bh_off = (size_t)bh * DH;

    // Q fragments (A-operand): aq[blk][ks], rows qbase+blk*16+c
    bf16x8 aq[2][4];
    #pragma unroll
    for (int blk = 0; blk < 2; blk++) {
        const float* qrow = Q + (size_t)(qbase + blk * 16 + c) * 4096 + bh_off;
        #pragma unroll
        for (int ks = 0; ks < 4; ks++) {
            const int d0 = ks * 32 + quad * 8;
            float4 f0 = *(const float4*)(qrow + d0);
            float4 f1 = *(const float4*)(qrow + d0 + 4);
            uint4 u;
            u.x = cvtpk(f0.x, f0.y); u.y = cvtpk(f0.z, f0.w);
            u.z = cvtpk(f1.x, f1.y); u.w = cvtpk(f1.z, f1.w);
            aq[blk][ks] = *(bf16x8*)&u;
        }
    }

    f32x4 oa[2][8];
    #pragma unroll
    for (int blk = 0; blk < 2; blk++)
        #pragma unroll
        for (int nb = 0; nb < 8; nb++) oa[blk][nb] = (f32x4){0.f, 0.f, 0.f, 0.f};
    float l[2][4];
    #pragma unroll
    for (int blk = 0; blk < 2; blk++)
        #pragma unroll
        for (int r = 0; r < 4; r++) l[blk][r] = 0.0f;

    const unsigned short* KpT = Kp + (size_t)bh * (NKT * 8192);
    const unsigned short* VpT = Vp + (size_t)bh * (NKT * 8192);
    const unsigned long long* mb0 = MB + (size_t)(b_i * SQ + qbase + quad * 4) * NKT;
    const unsigned long long* mb1 = mb0 + 16 * NKT;
    unsigned short* Pw = &P_lds[w * 2048];

    unsigned long long mrA[2][4], mrB[2][4];

    // prologue: stage tile 0 + its mask rows (8 DMA + 8 loads in flight)
    STAGE(K_lds[0], V_lds[0], 0);
    LOADMR(mrA, 0);

    for (int kt = 0; kt < NKT; kt += 2) {
        PIPE_STEP(K_lds[0], V_lds[0], mrA, K_lds[1], V_lds[1], mrB, kt + 1);
        PIPE_STEP(K_lds[1], V_lds[1], mrB, K_lds[0], V_lds[0], mrA, (kt + 2) & 31);
    }
    asm volatile("s_waitcnt vmcnt(0)" ::: "memory");

    // ---- epilogue: reduce l across 16 lanes, 1/l (0 if all masked), store ----
    #pragma unroll
    for (int blk = 0; blk < 2; blk++) {
        #pragma unroll
        for (int r = 0; r < 4; r++) {
            float t = l[blk][r];
            t += __shfl_xor(t, 1, 64);
            t += __shfl_xor(t, 2, 64);
            t += __shfl_xor(t, 4, 64);
            t += __shfl_xor(t, 8, 64);
            float inv = (t > 0.0f) ? (1.0f / t) : 0.0f;
            float* orow = out + (size_t)(qbase + blk * 16 + quad * 4 + r) * 4096 + bh_off;
            #pragma unroll
            for (int nb = 0; nb < 8; nb++)
                orow[nb * 16 + c] = oa[blk][nb][r] * inv;
        }
    }
}

// ---------------- fallback if workspace too small (unchanged) ----------------
__global__ __launch_bounds__(256)
void fa_fallback(const float* __restrict__ Q, const float* __restrict__ K,
                 const float* __restrict__ V, const int* __restrict__ mask,
                 float* __restrict__ out)
{
    __shared__ unsigned short K_lds[64 * 136];
    __shared__ unsigned short Vt_lds[128 * 72];
    __shared__ unsigned short P_lds[4 * 16 * 72];
    const int tid = threadIdx.x, w = tid >> 6, lane = tid & 63, quad = lane >> 4, c = lane & 15;
    const int gid = blockIdx.x, qtile = gid & 31, bh = gid >> 5, b_i = bh >> 4;
    const int q0 = qtile * 64 + w * 16;
    const size_t bh_off = (size_t)bh * DH;
    bf16x8 aq[4];
    {
        const float* qrow = Q + (size_t)(q0 + c) * 4096 + bh_off;
        #pragma unroll
        for (int ks = 0; ks < 4; ks++) {
            const int d0 = ks * 32 + quad * 8;
            float4 f0 = *(const float4*)(qrow + d0);
            float4 f1 = *(const float4*)(qrow + d0 + 4);
            bf16x8 a;
            a[0] = (short)f2b(f0.x); a[1] = (short)f2b(f0.y); a[2] = (short)f2b(f0.z); a[3] = (short)f2b(f0.w);
            a[4] = (short)f2b(f1.x); a[5] = (short)f2b(f1.y); a[6] = (short)f2b(f1.z); a[7] = (short)f2b(f1.w);
            aq[ks] = a;
        }
    }
    float m_i[4], l_i[4];
    #pragma unroll
    for (int r = 0; r < 4; r++) { m_i[r] = -INFINITY; l_i[r] = 0.0f; }
    f32x4 o_acc[8];
    #pragma unroll
    for (int nb = 0; nb < 8; nb++) o_acc[nb] = (f32x4){0.f, 0.f, 0.f, 0.f};
    const int srow = tid >> 2, scol = (tid & 3) * 4;
    const int* mbase = mask + (size_t)b_i * SQ * SQ;
    for (int kt = 0; kt < SQ; kt += 64) {
        __syncthreads();
        {
            const float* krow = K + (size_t)(kt + srow) * 4096 + bh_off;
            const float* vrow = V + (size_t)(kt + srow) * 4096 + bh_off;
            #pragma unroll
            for (int j = 0; j < 8; j++) {
                const int d0 = scol + j * 16;
                float4 kf = *(const float4*)(krow + d0);
                unsigned lo = (unsigned)f2b(kf.x) | ((unsigned)f2b(kf.y) << 16);
                unsigned hi = (unsigned)f2b(kf.z) | ((unsigned)f2b(kf.w) << 16);
                *(uint2*)&K_lds[srow * 136 + d0] = make_uint2(lo, hi);
                float4 vf = *(const float4*)(vrow + d0);
                Vt_lds[(d0 + 0) * 72 + srow] = f2b(vf.x);
                Vt_lds[(d0 + 1) * 72 + srow] = f2b(vf.y);
                Vt_lds[(d0 + 2) * 72 + srow] = f2b(vf.z);
                Vt_lds[(d0 + 3) * 72 + srow] = f2b(vf.w);
            }
        }
        __syncthreads();
        f32x4 s[4];
        #pragma unroll
        for (int nb = 0; nb < 4; nb++) s[nb] = (f32x4){0.f, 0.f, 0.f, 0.f};
        #pragma unroll
        for (int nb = 0; nb < 4; nb++)
            #pragma unroll
            for (int ks = 0; ks < 4; ks++) {
                bf16x8 bk = *(const bf16x8*)&K_lds[(nb * 16 + c) * 136 + ks * 32 + quad * 8];
                s[nb] = __builtin_amdgcn_mfma_f32_16x16x32_bf16(aq[ks], bk, s[nb], 0, 0, 0);
            }
        float rowmax[4];
        #pragma unroll
        for (int r = 0; r < 4; r++) rowmax[r] = -INFINITY;
        #pragma unroll
        for (int r = 0; r < 4; r++) {
            const int* mp = mbase + (size_t)(q0 + quad * 4 + r) * SQ + kt + c;
            #pragma unroll
            for (int nb = 0; nb < 4; nb++) {
                float v = s[nb][r] * SCALEF;
                if (mp[nb * 16] != 0) v = -10000.0f;
                s[nb][r] = v;
                rowmax[r] = fmaxf(rowmax[r], v);
            }
        }
        #pragma unroll
        for (int r = 0; r < 4; r++)
            #pragma unroll
            for (int off = 1; off < 16; off <<= 1)
                rowmax[r] = fmaxf(rowmax[r], __shfl_xor(rowmax[r], off, 64));
        float alpha[4], rowsum[4];
        #pragma unroll
        for (int r = 0; r < 4; r++) {
            float mn = fmaxf(m_i[r], rowmax[r]);
            alpha[r] = __expf(m_i[r] - mn);
            m_i[r] = mn;
            rowsum[r] = 0.0f;
        }
        #pragma unroll
        for (int r = 0; r < 4; r++)
            #pragma unroll
            for (int nb = 0; nb < 4; nb++) {
                float p = __expf(s[nb][r] - m_i[r]);
                rowsum[r] += p;
                P_lds[(w * 16 + quad * 4 + r) * 72 + nb * 16 + c] = f2b(p);
            }
        #pragma unroll
        for (int r = 0; r < 4; r++) {
            #pragma unroll
            for (int off = 1; off < 16; off <<= 1)
                rowsum[r] += __shfl_xor(rowsum[r], off, 64);
            l_i[r] = l_i[r] * alpha[r] + rowsum[r];
        }
        #pragma unroll
        for (int nb = 0; nb < 8; nb++)
            #pragma unroll
            for (int r = 0; r < 4; r++) o_acc[nb][r] *= alpha[r];
        bf16x8 ap[2];
        #pragma unroll
        for (int ks = 0; ks < 2; ks++)
            ap[ks] = *(const bf16x8*)&P_lds[(w * 16 + c) * 72 + ks * 32 + quad * 8];
        #pragma unroll
        for (int nb = 0; nb < 8; nb++)
            #pragma unroll
            for (int ks = 0; ks < 2; ks++) {
                bf16x8 bv = *(const bf16x8*)&Vt_lds[(nb * 16 + c) * 72 + ks * 32 + quad * 8];
                o_acc[nb] = __builtin_amdgcn_mfma_f32_16x16x32_bf16(ap[ks], bv, o_acc[nb], 0, 0, 0);
            }
    }
    float inv[4];
    #pragma unroll
    for (int r = 0; r < 4; r++) inv[r] = (m_i[r] > -9999.0f) ? (1.0f / l_i[r]) : 0.0f;
    #pragma unroll
    for (int r = 0; r < 4; r++) {
        float* orow = out + (size_t)(q0 + quad * 4 + r) * 4096 + bh_off;
        #pragma unroll
        for (int nb = 0; nb < 8; nb++) orow[nb * 16 + c] = o_acc[nb][r] * inv[r];
    }
}

extern "C" void kernel_launch(void* const* d_in, const int* in_sizes, int n_in,
                              void* d_out, int out_size, void* d_ws, size_t ws_size,
                              hipStream_t stream) {
    const float* Q    = (const float*)d_in[0];
    const float* K    = (const float*)d_in[1];
    const float* V    = (const float*)d_in[2];
    const int*   mask = (const int*)d_in[3];
    float* out = (float*)d_out;

    const size_t KP_BYTES = (size_t)32 * 32 * 8192 * 2;   // 16 MiB
    const size_t NEED = 2 * KP_BYTES + (size_t)4096 * NKT * 8;
    if (ws_size < NEED) {
        fa_fallback<<<dim3(1024), dim3(256), 0, stream>>>(Q, K, V, mask, out);
        return;
    }
    unsigned short* Kp = (unsigned short*)d_ws;
    unsigned short* Vp = (unsigned short*)((char*)d_ws + KP_BYTES);
    unsigned long long* MB = (unsigned long long*)((char*)d_ws + 2 * KP_BYTES);

    prep_all<<<dim3(7168), dim3(256), 0, stream>>>(K, V, mask, Kp, Vp, MB);
    fa2<<<dim3(512), dim3(256), 0, stream>>>(Q, Kp, Vp, MB, out);
}